// Round 27
// baseline (78.926 us; speedup 1.0000x reference)
//
#include <hip/hip_runtime.h>

#define WDIM  256
#define NSAMP 512
#define NSIG  32
#define NBLK  2048               // 512 samples x 4 j-quarters
#define QOFF  16                 // ints; queue table q[QOFF..]
#define WOFF  65536              // byte offset of W matrices inside d_ws

typedef float    f32x4 __attribute__((ext_vector_type(4)));
typedef _Float16 f16x4 __attribute__((ext_vector_type(4)));
typedef _Float16 f16x8 __attribute__((ext_vector_type(8)));
typedef __fp16   fp16x2 __attribute__((ext_vector_type(2)));

// Raw barrier without the __syncthreads vmcnt(0) drain: LDS visibility only,
// global prefetch loads stay in flight across it (T4 counted-vmcnt pattern).
#define LDS_BARRIER() do {                                         \
    asm volatile("s_waitcnt lgkmcnt(0)" ::: "memory");             \
    __builtin_amdgcn_s_barrier();                                  \
} while (0)

__device__ __forceinline__ int reflect(int q) {
    q = (q < 0) ? (-q - 1) : q;
    return (q >= WDIM) ? (2 * WDIM - 1 - q) : q;
}

// ---- kernel 1 (merged): blocks 0..255 build W matrices; block 256 the queue.
// W_s[i][r] = wz(r-i)+wz(-r-1-i)+wz(511-r-i); desc = samp|quarter<<9|step<<11|rad<<16.
__global__ __launch_bounds__(256) void build_all(const float* __restrict__ sigmas,
                                                 const int* __restrict__ steps,
                                                 _Float16* __restrict__ Wg,
                                                 int* __restrict__ q) {
    int t = threadIdx.x;
    if (blockIdx.x < 256) {
        __shared__ float wl[161];
        __shared__ float red;
        int s = blockIdx.x >> 3, og = blockIdx.x & 7;
        float sigma = sigmas[s];
        float radf = floorf(4.0f * sigma + 0.5f);
        if (t < 161) {
            float off = (float)(t - 80);
            float w = 0.0f;
            if (fabsf(off) <= radf) { float z = off / sigma; w = expf(-0.5f * z * z); }
            wl[t] = w;
        }
        __syncthreads();
        if (t < 64) {
            float v = wl[t] + wl[t + 64] + (t < 33 ? wl[t + 128] : 0.0f);
            #pragma unroll
            for (int o = 32; o > 0; o >>= 1) v += __shfl_down(v, o);
            if (t == 0) red = 1.0f / v;
        }
        __syncthreads();
        float rs = red;
        int i = t;
        _Float16* wrow = Wg + ((size_t)s << 16) + (i << 8);
        for (int rq = og * 4; rq < og * 4 + 4; ++rq) {
            f16x8 v;
            #pragma unroll
            for (int j = 0; j < 8; ++j) {
                int r = rq * 8 + j;
                int d1 = r - i, d2 = -r - 1 - i, d3 = 511 - r - i;
                float w = 0.0f;
                if (d1 >= -80 && d1 <= 80) w += wl[d1 + 80];
                if (d2 >= -80)             w += wl[d2 + 80];
                if (d3 <= 80)              w += wl[d3 + 80];
                v[j] = (_Float16)(w * rs);
            }
            *(f16x8*)(wrow + rq * 8) = v;
        }
    } else {
        __shared__ int hist[32];
        __shared__ int base[32];
        if (t < 32) hist[t] = 0;
        __syncthreads();
        int nb2[2], rd2[2], st2[2];
        #pragma unroll
        for (int k = 0; k < 2; ++k) {
            int samp = t + 256 * k;
            int st = steps[samp];
            float sigma = sigmas[st];
            int rad = (int)floorf(4.0f * sigma + 0.5f);
            st2[k] = st; rd2[k] = rad;
            nb2[k] = (2 * rad + 15) >> 3;
            atomicAdd(&hist[nb2[k]], 1);
        }
        __syncthreads();
        if (t == 0) {
            int acc = 0;
            for (int bin = 31; bin >= 0; --bin) { base[bin] = acc; acc += hist[bin]; }
        }
        __syncthreads();
        #pragma unroll
        for (int k = 0; k < 2; ++k) {
            int samp = t + 256 * k;
            int r = atomicAdd(&base[nb2[k]], 1);
            int x = r & 7;
            int p = r >> 3;
            #pragma unroll
            for (int jb = 0; jb < 4; ++jb)
                q[QOFF + (((p << 2) + jb) << 3) + x] =
                    samp | (jb << 9) | (st2[k] << 11) | (rd2[k] << 16);
        }
    }
}

// ---- kernel 2: fused MFMA blur, double-buffered staging, 1 barrier/tile. ----
// Identical to r26 except __launch_bounds__(256,4): LDS 40KB allows exactly
// 4 blocks/CU (160/40) and VGPR 72 << 512/4, so we let the scheduler have them.
template <bool QUEUED>
__global__ __launch_bounds__(256, 4) void blur_mfma(const float* __restrict__ in,
                                                    float* __restrict__ out,
                                                    const float* __restrict__ sigmas,
                                                    const int* __restrict__ steps,
                                                    const int* __restrict__ q,
                                                    const _Float16* __restrict__ Wg) {
    __shared__ alignas(16) _Float16 LDSU[20 * 1024];   // 40 KB
    // layout (halfs): XL buf p at p*8192 (2x16KB), WH buf p at 16384 + p*2048
    // (2x4KB), YT = LDSU (32KB, aliases XL dbuf which is dead in phase V).

    int b, j0, s, rad;
    if constexpr (QUEUED) {
        int d = q[QOFF + blockIdx.x];
        b = d & 511; j0 = ((d >> 9) & 3) << 6; s = (d >> 11) & 31; rad = (d >> 16) & 127;
    } else {
        int bid = blockIdx.x;
        int e = (bid & 7) * (NBLK / 8) + (bid >> 3);
        b = e >> 2; j0 = (e & 3) << 6;
        s = steps[b];
        rad = (int)floorf(4.0f * sigmas[s] + 0.5f);
    }
    const _Float16* Wm = Wg + ((size_t)s << 16);
    const float*    Xb = in + ((size_t)b << 16);

    int tt = threadIdx.x;
    int ln = tt & 63, wv = tt >> 6;
    int lm = ln & 15, lq = ln >> 4;
    int sr = tt >> 3;             // X stage row base (0..31)
    int sc = (tt & 7) * 4;        // X stage col
    int sj = tt >> 2;             // W stage j (0..63)
    int sw8 = (tt & 3) * 8;       // W stage c chunk

    int kh0 = max(0, j0 - rad) >> 5;
    int kh1 = min(WDIM - 1, j0 + 63 + rad) >> 5;

    f32x4 xs[8];                  // single staging register set (reissued)
    f16x8 wst;
    auto ldstage = [&](int kt) {  // coalesced loads (128B-contig row segments)
        const float* xp = Xb + (size_t)sr * WDIM + (kt << 5) + sc;
        #pragma unroll
        for (int k = 0; k < 8; ++k)
            xs[k] = *(const f32x4*)(xp + (size_t)(k * 32) * WDIM);
        wst = *(const f16x8*)(Wm + (size_t)(j0 + sj) * WDIM + (kt << 5) + sw8);
    };
    auto wrstage = [&](int p) {   // convert + swizzled LDS writes into buffer p
        _Float16* XL = LDSU + p * 8192;
        #pragma unroll
        for (int k = 0; k < 8; ++k) {
            int rr = sr + 32 * k;
            union { f16x4 v; fp16x2 h[2]; } u;
            u.h[0] = __builtin_amdgcn_cvt_pkrtz(xs[k][0], xs[k][1]);
            u.h[1] = __builtin_amdgcn_cvt_pkrtz(xs[k][2], xs[k][3]);
            *(f16x4*)&XL[rr * 32 + ((((sc >> 3) ^ (rr & 3)) << 3) + (sc & 7))] = u.v;
        }
        _Float16* WH = LDSU + 16384 + p * 2048;
        *(f16x8*)&WH[sj * 32 + (((tt & 3) ^ (sj & 3)) << 3)] = wst;
    };

    // ---------------- Phase H ----------------
    f32x4 acc[4][4];
    #pragma unroll
    for (int mt = 0; mt < 4; ++mt)
        #pragma unroll
        for (int nt = 0; nt < 4; ++nt) acc[mt][nt] = (f32x4)0.0f;

    // prologue: tile kh0 -> buf0, issue tile kh0+1
    ldstage(kh0);
    wrstage(0);
    if (kh0 + 1 <= kh1) ldstage(kh0 + 1);
    LDS_BARRIER();

    int cur = 0;
    for (int kt = kh0; kt <= kh1; ++kt) {
        if (kt < kh1) {
            wrstage(cur ^ 1);              // counted vmcnt wait (tile kt+1 loads)
            if (kt + 2 <= kh1) ldstage(kt + 2);   // reissue: in flight across barrier
        }
        _Float16* XL = LDSU + cur * 8192;
        _Float16* WH = LDSU + 16384 + cur * 2048;
        f16x8 bf[4];
        #pragma unroll
        for (int nt = 0; nt < 4; ++nt) {
            int j = nt * 16 + lm;
            bf[nt] = *(const f16x8*)&WH[j * 32 + ((lq ^ (j & 3)) << 3)];
        }
        #pragma unroll
        for (int mt = 0; mt < 4; ++mt) {
            int r = wv * 64 + mt * 16 + lm;
            f16x8 af = *(const f16x8*)&XL[r * 32 + ((lq ^ (r & 3)) << 3)];
            #pragma unroll
            for (int nt = 0; nt < 4; ++nt)
                acc[mt][nt] = __builtin_amdgcn_mfma_f32_16x16x32_f16(af, bf[nt], acc[mt][nt], 0, 0, 0);
        }
        LDS_BARRIER();   // ONE barrier per tile: publishes buf cur^1, retires reads of cur
        cur ^= 1;
    }

    // Yh^T -> YT (swizzled; XL dbuf dead after final barrier)
    _Float16* YT = LDSU;
    #pragma unroll
    for (int mt = 0; mt < 4; ++mt)
        #pragma unroll
        for (int nt = 0; nt < 4; ++nt) {
            int r4 = wv * 64 + mt * 16 + lq * 4;
            int j  = nt * 16 + lm;
            union { f16x4 v; fp16x2 h[2]; } u;
            u.h[0] = __builtin_amdgcn_cvt_pkrtz(acc[mt][nt][0], acc[mt][nt][1]);
            u.h[1] = __builtin_amdgcn_cvt_pkrtz(acc[mt][nt][2], acc[mt][nt][3]);
            *(f16x4*)&YT[j * 256 + ((((r4 >> 3) ^ (j & 7)) << 3) + (r4 & 7))] = u.v;
        }
    LDS_BARRIER();

    // ---------------- Phase V (barrier-free) ----------------
    f32x4 hac[4][4];
    #pragma unroll
    for (int mt = 0; mt < 4; ++mt)
        #pragma unroll
        for (int nt = 0; nt < 4; ++nt) hac[mt][nt] = (f32x4)0.0f;

    int ka[4], kb[4];
    #pragma unroll
    for (int mt = 0; mt < 4; ++mt) {
        int i0m = wv * 64 + mt * 16;
        ka[mt] = max(0, i0m - rad) >> 5;
        kb[mt] = min(WDIM - 1, i0m + 15 + rad) >> 5;
    }

    for (int kt = ka[0]; kt <= kb[3]; ++kt) {
        f16x8 bf[4];
        #pragma unroll
        for (int nt = 0; nt < 4; ++nt) {
            int j = nt * 16 + lm;
            bf[nt] = *(const f16x8*)&YT[j * 256 + ((((kt << 2) + lq) ^ (j & 7)) << 3)];
        }
        #pragma unroll
        for (int mt = 0; mt < 4; ++mt) {
            if (kt >= ka[mt] && kt <= kb[mt]) {
                f16x8 af = *(const f16x8*)(Wm + (size_t)(wv * 64 + mt * 16 + lm) * WDIM + (kt << 5) + lq * 8);
                #pragma unroll
                for (int nt = 0; nt < 4; ++nt)
                    hac[mt][nt] = __builtin_amdgcn_mfma_f32_16x16x32_f16(af, bf[nt], hac[mt][nt], 0, 0, 0);
            }
        }
    }

    float* ob = out + ((size_t)b << 16);
    #pragma unroll
    for (int mt = 0; mt < 4; ++mt)
        #pragma unroll
        for (int nt = 0; nt < 4; ++nt)
            #pragma unroll
            for (int g = 0; g < 4; ++g)
                ob[(size_t)(wv * 64 + mt * 16 + lq * 4 + g) * WDIM + j0 + nt * 16 + lm] = hac[mt][nt][g];
}

// ---------- fallback path (only if ws too small; needs no workspace) ----------
__device__ __forceinline__ int make_weights161(int b, const float* __restrict__ sigmas,
                                               const int* __restrict__ steps,
                                               float* wl, float* red) {
    int t = threadIdx.x;
    float sigma = sigmas[steps[b]];
    float radf = floorf(4.0f * sigma + 0.5f);
    if (t < 192) {
        float w = 0.0f;
        if (t < 161) {
            float off = (float)(t - 80);
            if (fabsf(off) <= radf) { float z = off / sigma; w = expf(-0.5f * z * z); }
        }
        wl[t] = w;
    }
    __syncthreads();
    if (t < 64) {
        float v = wl[t] + wl[t + 64] + wl[t + 128];
        #pragma unroll
        for (int o = 32; o > 0; o >>= 1) v += __shfl_down(v, o);
        if (t == 0) red[0] = 1.0f / v;
    }
    __syncthreads();
    float rs = red[0];
    if (t < 161) wl[t] *= rs;
    __syncthreads();
    return (int)radf;
}

__global__ __launch_bounds__(256) void vblur_nt(const float* __restrict__ in,
                                                float* __restrict__ out,
                                                const float* __restrict__ sigmas,
                                                const int* __restrict__ steps) {
    __shared__ float wl[192];
    __shared__ float red[1];
    int bid = blockIdx.x;
    int b = bid >> 4, i0 = (bid & 15) * 16;
    int rad = make_weights161(b, sigmas, steps, wl, red);
    int j = threadIdx.x;
    const float* inb = in + (size_t)b * WDIM * WDIM;
    float acc[16];
    #pragma unroll
    for (int ii = 0; ii < 16; ++ii) acc[ii] = 0.0f;
    for (int u = -rad; u <= rad; ++u) {
        float w = wl[80 + u];
        #pragma unroll
        for (int ii = 0; ii < 16; ++ii)
            acc[ii] = fmaf(w, inb[reflect(i0 + ii + u) * WDIM + j], acc[ii]);
    }
    #pragma unroll
    for (int ii = 0; ii < 16; ++ii)
        out[((size_t)b * WDIM + (i0 + ii)) * WDIM + j] = acc[ii];
}

__global__ __launch_bounds__(256) void hblur_inplace(float* __restrict__ buf,
                                                     const float* __restrict__ sigmas,
                                                     const int* __restrict__ steps) {
    __shared__ float wl[192];
    __shared__ float red[1];
    __shared__ float rp[WDIM + 160];
    int bid = blockIdx.x;
    int b = bid >> 8, i = bid & 255;
    float* row = buf + ((size_t)b * WDIM + i) * WDIM;
    int t = threadIdx.x;
    for (int s = t; s < WDIM + 160; s += 256) rp[s] = row[reflect(s - 80)];
    int rad = make_weights161(b, sigmas, steps, wl, red);
    float acc = 0.0f;
    for (int u = -rad; u <= rad; ++u) acc = fmaf(wl[80 + u], rp[80 + t + u], acc);
    row[t] = acc;
}
// --------------------------------------------------------------------------------

extern "C" void kernel_launch(void* const* d_in, const int* in_sizes, int n_in,
                              void* d_out, int out_size, void* d_ws, size_t ws_size,
                              hipStream_t stream) {
    const float* x     = (const float*)d_in[0];
    const float* sig   = (const float*)d_in[1];
    const int*   steps = (const int*)d_in[2];
    float* out = (float*)d_out;

    const size_t need = (size_t)WOFF + (size_t)NSIG * WDIM * WDIM * 2;
    if (ws_size >= need) {
        int* q = (int*)d_ws;
        _Float16* Wg = (_Float16*)((char*)d_ws + WOFF);
        build_all<<<257, 256, 0, stream>>>(sig, steps, Wg, q);
        blur_mfma<true><<<NBLK, 256, 0, stream>>>(x, out, sig, steps, q, Wg);
    } else {
        vblur_nt<<<NSAMP * 16, 256, 0, stream>>>(x, out, sig, steps);
        hblur_inplace<<<NSAMP * WDIM, 256, 0, stream>>>(out, sig, steps);
    }
}

// Round 28
// 72.176 us; speedup vs baseline: 1.0935x; 1.0935x over previous
//
#include <hip/hip_runtime.h>

#define WDIM  256
#define NSAMP 512
#define NSIG  32
#define NBLK  2048               // 512 samples x 4 j-quarters
#define QOFF  16                 // ints; queue table q[QOFF..]
#define WOFF  65536              // byte offset of W matrices inside d_ws

typedef float    f32x4 __attribute__((ext_vector_type(4)));
typedef _Float16 f16x4 __attribute__((ext_vector_type(4)));
typedef _Float16 f16x8 __attribute__((ext_vector_type(8)));
typedef __fp16   fp16x2 __attribute__((ext_vector_type(2)));

// Raw barrier without the __syncthreads vmcnt(0) drain: LDS visibility only,
// global prefetch loads stay in flight across it (T4 counted-vmcnt pattern).
#define LDS_BARRIER() do {                                         \
    asm volatile("s_waitcnt lgkmcnt(0)" ::: "memory");             \
    __builtin_amdgcn_s_barrier();                                  \
} while (0)

__device__ __forceinline__ int reflect(int q) {
    q = (q < 0) ? (-q - 1) : q;
    return (q >= WDIM) ? (2 * WDIM - 1 - q) : q;
}

// ---- kernel 1 (merged): blocks 0..255 build W matrices; block 256 the queue.
// W_s[i][r] = wz(r-i)+wz(-r-1-i)+wz(511-r-i); desc = samp|quarter<<9|step<<11|rad<<16.
__global__ __launch_bounds__(256) void build_all(const float* __restrict__ sigmas,
                                                 const int* __restrict__ steps,
                                                 _Float16* __restrict__ Wg,
                                                 int* __restrict__ q) {
    int t = threadIdx.x;
    if (blockIdx.x < 256) {
        __shared__ float wl[161];
        __shared__ float red;
        int s = blockIdx.x >> 3, og = blockIdx.x & 7;
        float sigma = sigmas[s];
        float radf = floorf(4.0f * sigma + 0.5f);
        if (t < 161) {
            float off = (float)(t - 80);
            float w = 0.0f;
            if (fabsf(off) <= radf) { float z = off / sigma; w = expf(-0.5f * z * z); }
            wl[t] = w;
        }
        __syncthreads();
        if (t < 64) {
            float v = wl[t] + wl[t + 64] + (t < 33 ? wl[t + 128] : 0.0f);
            #pragma unroll
            for (int o = 32; o > 0; o >>= 1) v += __shfl_down(v, o);
            if (t == 0) red = 1.0f / v;
        }
        __syncthreads();
        float rs = red;
        int i = t;
        _Float16* wrow = Wg + ((size_t)s << 16) + (i << 8);
        for (int rq = og * 4; rq < og * 4 + 4; ++rq) {
            f16x8 v;
            #pragma unroll
            for (int j = 0; j < 8; ++j) {
                int r = rq * 8 + j;
                int d1 = r - i, d2 = -r - 1 - i, d3 = 511 - r - i;
                float w = 0.0f;
                if (d1 >= -80 && d1 <= 80) w += wl[d1 + 80];
                if (d2 >= -80)             w += wl[d2 + 80];
                if (d3 <= 80)              w += wl[d3 + 80];
                v[j] = (_Float16)(w * rs);
            }
            *(f16x8*)(wrow + rq * 8) = v;
        }
    } else {
        __shared__ int hist[32];
        __shared__ int base[32];
        if (t < 32) hist[t] = 0;
        __syncthreads();
        int nb2[2], rd2[2], st2[2];
        #pragma unroll
        for (int k = 0; k < 2; ++k) {
            int samp = t + 256 * k;
            int st = steps[samp];
            float sigma = sigmas[st];
            int rad = (int)floorf(4.0f * sigma + 0.5f);
            st2[k] = st; rd2[k] = rad;
            nb2[k] = (2 * rad + 15) >> 3;
            atomicAdd(&hist[nb2[k]], 1);
        }
        __syncthreads();
        if (t == 0) {
            int acc = 0;
            for (int bin = 31; bin >= 0; --bin) { base[bin] = acc; acc += hist[bin]; }
        }
        __syncthreads();
        #pragma unroll
        for (int k = 0; k < 2; ++k) {
            int samp = t + 256 * k;
            int r = atomicAdd(&base[nb2[k]], 1);
            int x = r & 7;
            int p = r >> 3;
            #pragma unroll
            for (int jb = 0; jb < 4; ++jb)
                q[QOFF + (((p << 2) + jb) << 3) + x] =
                    samp | (jb << 9) | (st2[k] << 11) | (rd2[k] << 16);
        }
    }
}

// ---- kernel 2: fused MFMA blur (r26 best config) + V-phase W pre-issue. ----
// Phase H: X+W staged into alternating LDS buffers; per tile: {wr(next buf)
//   [counted vmcnt] -> reissue loads(kt+2) -> compute(cur) -> LDS_BARRIER}.
// Before the YT barrier: issue phase V's first W A-frags (in flight across it).
// Phase V: barrier-free; A=W direct (L2-hot), B=YT LDS (aliases dead XL dbuf).
template <bool QUEUED>
__global__ __launch_bounds__(256, 3) void blur_mfma(const float* __restrict__ in,
                                                    float* __restrict__ out,
                                                    const float* __restrict__ sigmas,
                                                    const int* __restrict__ steps,
                                                    const int* __restrict__ q,
                                                    const _Float16* __restrict__ Wg) {
    __shared__ alignas(16) _Float16 LDSU[20 * 1024];   // 40 KB
    // layout (halfs): XL buf p at p*8192 (2x16KB), WH buf p at 16384 + p*2048
    // (2x4KB), YT = LDSU (32KB, aliases XL dbuf which is dead in phase V).

    int b, j0, s, rad;
    if constexpr (QUEUED) {
        int d = q[QOFF + blockIdx.x];
        b = d & 511; j0 = ((d >> 9) & 3) << 6; s = (d >> 11) & 31; rad = (d >> 16) & 127;
    } else {
        int bid = blockIdx.x;
        int e = (bid & 7) * (NBLK / 8) + (bid >> 3);
        b = e >> 2; j0 = (e & 3) << 6;
        s = steps[b];
        rad = (int)floorf(4.0f * sigmas[s] + 0.5f);
    }
    const _Float16* Wm = Wg + ((size_t)s << 16);
    const float*    Xb = in + ((size_t)b << 16);

    int tt = threadIdx.x;
    int ln = tt & 63, wv = tt >> 6;
    int lm = ln & 15, lq = ln >> 4;
    int sr = tt >> 3;             // X stage row base (0..31)
    int sc = (tt & 7) * 4;        // X stage col
    int sj = tt >> 2;             // W stage j (0..63)
    int sw8 = (tt & 3) * 8;       // W stage c chunk

    int kh0 = max(0, j0 - rad) >> 5;
    int kh1 = min(WDIM - 1, j0 + 63 + rad) >> 5;

    f32x4 xs[8];                  // single staging register set (reissued)
    f16x8 wst;
    auto ldstage = [&](int kt) {  // coalesced loads (128B-contig row segments)
        const float* xp = Xb + (size_t)sr * WDIM + (kt << 5) + sc;
        #pragma unroll
        for (int k = 0; k < 8; ++k)
            xs[k] = *(const f32x4*)(xp + (size_t)(k * 32) * WDIM);
        wst = *(const f16x8*)(Wm + (size_t)(j0 + sj) * WDIM + (kt << 5) + sw8);
    };
    auto wrstage = [&](int p) {   // convert + swizzled LDS writes into buffer p
        _Float16* XL = LDSU + p * 8192;
        #pragma unroll
        for (int k = 0; k < 8; ++k) {
            int rr = sr + 32 * k;
            union { f16x4 v; fp16x2 h[2]; } u;
            u.h[0] = __builtin_amdgcn_cvt_pkrtz(xs[k][0], xs[k][1]);
            u.h[1] = __builtin_amdgcn_cvt_pkrtz(xs[k][2], xs[k][3]);
            *(f16x4*)&XL[rr * 32 + ((((sc >> 3) ^ (rr & 3)) << 3) + (sc & 7))] = u.v;
        }
        _Float16* WH = LDSU + 16384 + p * 2048;
        *(f16x8*)&WH[sj * 32 + (((tt & 3) ^ (sj & 3)) << 3)] = wst;
    };

    // ---------------- Phase H ----------------
    f32x4 acc[4][4];
    #pragma unroll
    for (int mt = 0; mt < 4; ++mt)
        #pragma unroll
        for (int nt = 0; nt < 4; ++nt) acc[mt][nt] = (f32x4)0.0f;

    // prologue: tile kh0 -> buf0, issue tile kh0+1
    ldstage(kh0);
    wrstage(0);
    if (kh0 + 1 <= kh1) ldstage(kh0 + 1);
    LDS_BARRIER();

    int cur = 0;
    for (int kt = kh0; kt <= kh1; ++kt) {
        if (kt < kh1) {
            wrstage(cur ^ 1);              // counted vmcnt wait (tile kt+1 loads)
            if (kt + 2 <= kh1) ldstage(kt + 2);   // reissue: in flight across barrier
        }
        _Float16* XL = LDSU + cur * 8192;
        _Float16* WH = LDSU + 16384 + cur * 2048;
        f16x8 bf[4];
        #pragma unroll
        for (int nt = 0; nt < 4; ++nt) {
            int j = nt * 16 + lm;
            bf[nt] = *(const f16x8*)&WH[j * 32 + ((lq ^ (j & 3)) << 3)];
        }
        #pragma unroll
        for (int mt = 0; mt < 4; ++mt) {
            int r = wv * 64 + mt * 16 + lm;
            f16x8 af = *(const f16x8*)&XL[r * 32 + ((lq ^ (r & 3)) << 3)];
            #pragma unroll
            for (int nt = 0; nt < 4; ++nt)
                acc[mt][nt] = __builtin_amdgcn_mfma_f32_16x16x32_f16(af, bf[nt], acc[mt][nt], 0, 0, 0);
        }
        LDS_BARRIER();   // ONE barrier per tile: publishes buf cur^1, retires reads of cur
        cur ^= 1;
    }

    // V-phase K ranges (needed for the pre-issue below)
    int ka[4], kb[4];
    #pragma unroll
    for (int mt = 0; mt < 4; ++mt) {
        int i0m = wv * 64 + mt * 16;
        ka[mt] = max(0, i0m - rad) >> 5;
        kb[mt] = min(WDIM - 1, i0m + 15 + rad) >> 5;
    }

    // Pre-issue phase V's first W A-frags (global loads; in flight across barrier)
    f16x8 af0[4];
    {
        int kt0v = ka[0];
        #pragma unroll
        for (int mt = 0; mt < 4; ++mt)
            af0[mt] = *(const f16x8*)(Wm + (size_t)(wv * 64 + mt * 16 + lm) * WDIM + (kt0v << 5) + lq * 8);
    }

    // Yh^T -> YT (swizzled; XL dbuf dead after final barrier)
    _Float16* YT = LDSU;
    #pragma unroll
    for (int mt = 0; mt < 4; ++mt)
        #pragma unroll
        for (int nt = 0; nt < 4; ++nt) {
            int r4 = wv * 64 + mt * 16 + lq * 4;
            int j  = nt * 16 + lm;
            union { f16x4 v; fp16x2 h[2]; } u;
            u.h[0] = __builtin_amdgcn_cvt_pkrtz(acc[mt][nt][0], acc[mt][nt][1]);
            u.h[1] = __builtin_amdgcn_cvt_pkrtz(acc[mt][nt][2], acc[mt][nt][3]);
            *(f16x4*)&YT[j * 256 + ((((r4 >> 3) ^ (j & 7)) << 3) + (r4 & 7))] = u.v;
        }
    LDS_BARRIER();

    // ---------------- Phase V (barrier-free) ----------------
    f32x4 hac[4][4];
    #pragma unroll
    for (int mt = 0; mt < 4; ++mt)
        #pragma unroll
        for (int nt = 0; nt < 4; ++nt) hac[mt][nt] = (f32x4)0.0f;

    for (int kt = ka[0]; kt <= kb[3]; ++kt) {
        f16x8 bf[4];
        #pragma unroll
        for (int nt = 0; nt < 4; ++nt) {
            int j = nt * 16 + lm;
            bf[nt] = *(const f16x8*)&YT[j * 256 + ((((kt << 2) + lq) ^ (j & 7)) << 3)];
        }
        #pragma unroll
        for (int mt = 0; mt < 4; ++mt) {
            if (kt >= ka[mt] && kt <= kb[mt]) {
                f16x8 af = (kt == ka[0]) ? af0[mt]
                    : *(const f16x8*)(Wm + (size_t)(wv * 64 + mt * 16 + lm) * WDIM + (kt << 5) + lq * 8);
                #pragma unroll
                for (int nt = 0; nt < 4; ++nt)
                    hac[mt][nt] = __builtin_amdgcn_mfma_f32_16x16x32_f16(af, bf[nt], hac[mt][nt], 0, 0, 0);
            }
        }
    }

    float* ob = out + ((size_t)b << 16);
    #pragma unroll
    for (int mt = 0; mt < 4; ++mt)
        #pragma unroll
        for (int nt = 0; nt < 4; ++nt)
            #pragma unroll
            for (int g = 0; g < 4; ++g)
                ob[(size_t)(wv * 64 + mt * 16 + lq * 4 + g) * WDIM + j0 + nt * 16 + lm] = hac[mt][nt][g];
}

// ---------- fallback path (only if ws too small; needs no workspace) ----------
__device__ __forceinline__ int make_weights161(int b, const float* __restrict__ sigmas,
                                               const int* __restrict__ steps,
                                               float* wl, float* red) {
    int t = threadIdx.x;
    float sigma = sigmas[steps[b]];
    float radf = floorf(4.0f * sigma + 0.5f);
    if (t < 192) {
        float w = 0.0f;
        if (t < 161) {
            float off = (float)(t - 80);
            if (fabsf(off) <= radf) { float z = off / sigma; w = expf(-0.5f * z * z); }
        }
        wl[t] = w;
    }
    __syncthreads();
    if (t < 64) {
        float v = wl[t] + wl[t + 64] + wl[t + 128];
        #pragma unroll
        for (int o = 32; o > 0; o >>= 1) v += __shfl_down(v, o);
        if (t == 0) red[0] = 1.0f / v;
    }
    __syncthreads();
    float rs = red[0];
    if (t < 161) wl[t] *= rs;
    __syncthreads();
    return (int)radf;
}

__global__ __launch_bounds__(256) void vblur_nt(const float* __restrict__ in,
                                                float* __restrict__ out,
                                                const float* __restrict__ sigmas,
                                                const int* __restrict__ steps) {
    __shared__ float wl[192];
    __shared__ float red[1];
    int bid = blockIdx.x;
    int b = bid >> 4, i0 = (bid & 15) * 16;
    int rad = make_weights161(b, sigmas, steps, wl, red);
    int j = threadIdx.x;
    const float* inb = in + (size_t)b * WDIM * WDIM;
    float acc[16];
    #pragma unroll
    for (int ii = 0; ii < 16; ++ii) acc[ii] = 0.0f;
    for (int u = -rad; u <= rad; ++u) {
        float w = wl[80 + u];
        #pragma unroll
        for (int ii = 0; ii < 16; ++ii)
            acc[ii] = fmaf(w, inb[reflect(i0 + ii + u) * WDIM + j], acc[ii]);
    }
    #pragma unroll
    for (int ii = 0; ii < 16; ++ii)
        out[((size_t)b * WDIM + (i0 + ii)) * WDIM + j] = acc[ii];
}

__global__ __launch_bounds__(256) void hblur_inplace(float* __restrict__ buf,
                                                     const float* __restrict__ sigmas,
                                                     const int* __restrict__ steps) {
    __shared__ float wl[192];
    __shared__ float red[1];
    __shared__ float rp[WDIM + 160];
    int bid = blockIdx.x;
    int b = bid >> 8, i = bid & 255;
    float* row = buf + ((size_t)b * WDIM + i) * WDIM;
    int t = threadIdx.x;
    for (int s = t; s < WDIM + 160; s += 256) rp[s] = row[reflect(s - 80)];
    int rad = make_weights161(b, sigmas, steps, wl, red);
    float acc = 0.0f;
    for (int u = -rad; u <= rad; ++u) acc = fmaf(wl[80 + u], rp[80 + t + u], acc);
    row[t] = acc;
}
// --------------------------------------------------------------------------------

extern "C" void kernel_launch(void* const* d_in, const int* in_sizes, int n_in,
                              void* d_out, int out_size, void* d_ws, size_t ws_size,
                              hipStream_t stream) {
    const float* x     = (const float*)d_in[0];
    const float* sig   = (const float*)d_in[1];
    const int*   steps = (const int*)d_in[2];
    float* out = (float*)d_out;

    const size_t need = (size_t)WOFF + (size_t)NSIG * WDIM * WDIM * 2;
    if (ws_size >= need) {
        int* q = (int*)d_ws;
        _Float16* Wg = (_Float16*)((char*)d_ws + WOFF);
        build_all<<<257, 256, 0, stream>>>(sig, steps, Wg, q);
        blur_mfma<true><<<NBLK, 256, 0, stream>>>(x, out, sig, steps, q, Wg);
    } else {
        vblur_nt<<<NSAMP * 16, 256, 0, stream>>>(x, out, sig, steps);
        hblur_inplace<<<NSAMP * WDIM, 256, 0, stream>>>(out, sig, steps);
    }
}